// Round 1
// baseline (515.154 us; speedup 1.0000x reference)
//
#include <hip/hip_runtime.h>

// Affinity propagation: 24 Jacobi iterations of an 8-neighbor weighted stencil.
// OFFSETS (dy,dx): (-1,-1),(-1,0),(-1,1),(0,-1),(0,1),(1,-1),(1,0),(1,1)

#define EPSV 1e-6f

// ---------------------------------------------------------------------------
// Kernel 1: normalize guidance -> per-pixel 8 weights (AoS), bias, init out.
// gate_wb[b,c,y,x] = guidance[b,c,y+dy_c,x+dx_c] (zero outside), then
// normalized by sum |.| (clamped at EPS). bias = (1 - sum w) * raw.
// ---------------------------------------------------------------------------
__global__ __launch_bounds__(256) void precompute_kernel(
    const float* __restrict__ guidance, const float* __restrict__ raw,
    float* __restrict__ wgt, float* __restrict__ bias, float* __restrict__ out,
    int B, int H, int W)
{
    int idx = blockIdx.x * blockDim.x + threadIdx.x;
    int total = B * H * W;
    if (idx >= total) return;
    int x = idx % W;
    int y = (idx / W) % H;
    int b = idx / (W * H);

    const int dy[8] = {-1,-1,-1, 0, 0, 1, 1, 1};
    const int dx[8] = {-1, 0, 1,-1, 1,-1, 0, 1};

    float g[8];
    float s = 0.f;
#pragma unroll
    for (int c = 0; c < 8; ++c) {
        int yy = y + dy[c], xx = x + dx[c];
        float v = 0.f;
        if (yy >= 0 && yy < H && xx >= 0 && xx < W)
            v = guidance[(((size_t)b * 8 + c) * H + yy) * W + xx];
        g[c] = v;
        s += fabsf(v);
    }
    float inv = 1.f / fmaxf(s, EPSV);
    float wsum = 0.f;
#pragma unroll
    for (int c = 0; c < 8; ++c) { g[c] *= inv; wsum += g[c]; }

    float r = raw[idx];
    float4* wq = (float4*)(wgt + (size_t)idx * 8);
    wq[0] = make_float4(g[0], g[1], g[2], g[3]);
    wq[1] = make_float4(g[4], g[5], g[6], g[7]);
    bias[idx] = (1.f - wsum) * r;
    out[idx] = r;
}

// ---------------------------------------------------------------------------
// Kernel 2: one stencil pass, 4 pixels per thread (float4).
// result[y,x] = bias[y,x] + sum_c w_c[y,x] * src[y+dy_c, x+dx_c]  (zero pad)
// ---------------------------------------------------------------------------
__global__ __launch_bounds__(256) void prop_kernel(
    const float* __restrict__ src, const float* __restrict__ wgt,
    const float* __restrict__ bias, float* __restrict__ dst,
    int B, int H, int W)
{
    int g4 = blockIdx.x * blockDim.x + threadIdx.x;   // pixel-group id (4 px)
    int gpr = W >> 2;                                 // groups per row
    int total = B * H * gpr;
    if (g4 >= total) return;
    int gx  = g4 % gpr;
    int tmp = g4 / gpr;
    int y = tmp % H;
    int b = tmp / H;
    int x0 = gx << 2;

    const float* plane = src + (size_t)b * H * W;

    float um[6], cc[6], dn[6];
    {
        const float* row = plane + (size_t)y * W;
        float4 v = *(const float4*)(row + x0);
        cc[1] = v.x; cc[2] = v.y; cc[3] = v.z; cc[4] = v.w;
        cc[0] = (x0 > 0)     ? row[x0 - 1] : 0.f;
        cc[5] = (x0 + 4 < W) ? row[x0 + 4] : 0.f;
    }
    if (y > 0) {
        const float* row = plane + (size_t)(y - 1) * W;
        float4 v = *(const float4*)(row + x0);
        um[1] = v.x; um[2] = v.y; um[3] = v.z; um[4] = v.w;
        um[0] = (x0 > 0)     ? row[x0 - 1] : 0.f;
        um[5] = (x0 + 4 < W) ? row[x0 + 4] : 0.f;
    } else {
        um[0] = um[1] = um[2] = um[3] = um[4] = um[5] = 0.f;
    }
    if (y + 1 < H) {
        const float* row = plane + (size_t)(y + 1) * W;
        float4 v = *(const float4*)(row + x0);
        dn[1] = v.x; dn[2] = v.y; dn[3] = v.z; dn[4] = v.w;
        dn[0] = (x0 > 0)     ? row[x0 - 1] : 0.f;
        dn[5] = (x0 + 4 < W) ? row[x0 + 4] : 0.f;
    } else {
        dn[0] = dn[1] = dn[2] = dn[3] = dn[4] = dn[5] = 0.f;
    }

    const float4* wq = (const float4*)(wgt + (size_t)g4 * 32);
    float4 bi = *(const float4*)(bias + (size_t)g4 * 4);
    float bv[4] = {bi.x, bi.y, bi.z, bi.w};
    float out[4];
#pragma unroll
    for (int i = 0; i < 4; ++i) {
        float4 wa = wq[i * 2];
        float4 wb = wq[i * 2 + 1];
        float acc = bv[i];
        acc += wa.x * um[i]     + wa.y * um[i + 1] + wa.z * um[i + 2];
        acc += wa.w * cc[i]     + wb.x * cc[i + 2];
        acc += wb.y * dn[i]     + wb.z * dn[i + 1] + wb.w * dn[i + 2];
        out[i] = acc;
    }
    *(float4*)(dst + (size_t)g4 * 4) = make_float4(out[0], out[1], out[2], out[3]);
}

// ---------------------------------------------------------------------------
extern "C" void kernel_launch(void* const* d_in, const int* in_sizes, int n_in,
                              void* d_out, int out_size, void* d_ws, size_t ws_size,
                              hipStream_t stream) {
    const float* guidance = (const float*)d_in[0];
    const float* raw      = (const float*)d_in[1];
    float* out = (float*)d_out;

    const int B = 8, H = 480, W = 640;
    const int PROP_TIME = 24;
    const size_t npix = (size_t)B * H * W;

    // Workspace layout: weights (8*npix f32) | bias (npix f32) | tmp (npix f32)
    float* wgt  = (float*)d_ws;
    float* bias = wgt + npix * 8;
    float* tmpb = bias + npix;

    {
        int total = (int)npix;
        int blocks = (total + 255) / 256;
        precompute_kernel<<<blocks, 256, 0, stream>>>(guidance, raw, wgt, bias,
                                                      out, B, H, W);
    }

    int total4 = (int)(npix / 4);
    int blocks = (total4 + 255) / 256;
    float* a = out;   // result lives here after init
    float* bb = tmpb;
    for (int t = 0; t < PROP_TIME; ++t) {
        prop_kernel<<<blocks, 256, 0, stream>>>(a, wgt, bias, bb, B, H, W);
        float* sw = a; a = bb; bb = sw;
    }
    // PROP_TIME is even -> final result is back in d_out.
}

// Round 2
// 342.958 us; speedup vs baseline: 1.5021x; 1.5021x over previous
//
#include <hip/hip_runtime.h>
#include <hip/hip_fp16.h>

// Affinity propagation: 24 Jacobi iterations of an 8-neighbor weighted stencil.
// OFFSETS (dy,dx): (-1,-1),(-1,0),(-1,1),(0,-1),(0,1),(1,-1),(1,0),(1,1)
// Round 2: weights stored as fp16 (16 B/pixel) -> per-pass traffic 108->69 MB.

#define EPSV 1e-6f

typedef __attribute__((ext_vector_type(8))) _Float16 half8;

// ---------------------------------------------------------------------------
// Kernel 1: normalize guidance -> per-pixel 8 fp16 weights (AoS), fp32 bias,
// init out. gate_wb[b,c,y,x] = guidance[b,c,y+dy_c,x+dx_c] (zero outside),
// normalized by sum |.| (clamped at EPS). bias = (1 - sum w) * raw.
// ---------------------------------------------------------------------------
__global__ __launch_bounds__(256) void precompute_kernel(
    const float* __restrict__ guidance, const float* __restrict__ raw,
    half8* __restrict__ wgt, float* __restrict__ bias, float* __restrict__ out,
    int B, int H, int W)
{
    int idx = blockIdx.x * blockDim.x + threadIdx.x;
    int total = B * H * W;
    if (idx >= total) return;
    int x = idx % W;
    int y = (idx / W) % H;
    int b = idx / (W * H);

    const int dy[8] = {-1,-1,-1, 0, 0, 1, 1, 1};
    const int dx[8] = {-1, 0, 1,-1, 1,-1, 0, 1};

    float g[8];
    float s = 0.f;
#pragma unroll
    for (int c = 0; c < 8; ++c) {
        int yy = y + dy[c], xx = x + dx[c];
        float v = 0.f;
        if (yy >= 0 && yy < H && xx >= 0 && xx < W)
            v = guidance[(((size_t)b * 8 + c) * H + yy) * W + xx];
        g[c] = v;
        s += fabsf(v);
    }
    float inv = 1.f / fmaxf(s, EPSV);
    float wsum = 0.f;
#pragma unroll
    for (int c = 0; c < 8; ++c) { g[c] *= inv; wsum += g[c]; }

    half8 hw;
#pragma unroll
    for (int c = 0; c < 8; ++c) hw[c] = (_Float16)g[c];
    wgt[idx] = hw;

    float r = raw[idx];
    bias[idx] = (1.f - wsum) * r;
    out[idx] = r;
}

// ---------------------------------------------------------------------------
// Kernel 2: one stencil pass, 4 pixels per thread (float4 src/dst, half8 wgt).
// result[y,x] = bias[y,x] + sum_c w_c[y,x] * src[y+dy_c, x+dx_c]  (zero pad)
// ---------------------------------------------------------------------------
__global__ __launch_bounds__(256) void prop_kernel(
    const float* __restrict__ src, const half8* __restrict__ wgt,
    const float* __restrict__ bias, float* __restrict__ dst,
    int B, int H, int W)
{
    int g4 = blockIdx.x * blockDim.x + threadIdx.x;   // pixel-group id (4 px)
    int gpr = W >> 2;                                 // groups per row
    int total = B * H * gpr;
    if (g4 >= total) return;
    int gx  = g4 % gpr;
    int tmp = g4 / gpr;
    int y = tmp % H;
    int b = tmp / H;
    int x0 = gx << 2;

    const float* plane = src + (size_t)b * H * W;

    float um[6], cc[6], dn[6];
    {
        const float* row = plane + (size_t)y * W;
        float4 v = *(const float4*)(row + x0);
        cc[1] = v.x; cc[2] = v.y; cc[3] = v.z; cc[4] = v.w;
        cc[0] = (x0 > 0)     ? row[x0 - 1] : 0.f;
        cc[5] = (x0 + 4 < W) ? row[x0 + 4] : 0.f;
    }
    if (y > 0) {
        const float* row = plane + (size_t)(y - 1) * W;
        float4 v = *(const float4*)(row + x0);
        um[1] = v.x; um[2] = v.y; um[3] = v.z; um[4] = v.w;
        um[0] = (x0 > 0)     ? row[x0 - 1] : 0.f;
        um[5] = (x0 + 4 < W) ? row[x0 + 4] : 0.f;
    } else {
        um[0] = um[1] = um[2] = um[3] = um[4] = um[5] = 0.f;
    }
    if (y + 1 < H) {
        const float* row = plane + (size_t)(y + 1) * W;
        float4 v = *(const float4*)(row + x0);
        dn[1] = v.x; dn[2] = v.y; dn[3] = v.z; dn[4] = v.w;
        dn[0] = (x0 > 0)     ? row[x0 - 1] : 0.f;
        dn[5] = (x0 + 4 < W) ? row[x0 + 4] : 0.f;
    } else {
        dn[0] = dn[1] = dn[2] = dn[3] = dn[4] = dn[5] = 0.f;
    }

    float4 bi = *(const float4*)(bias + (size_t)g4 * 4);
    float bv[4] = {bi.x, bi.y, bi.z, bi.w};
    float out[4];
#pragma unroll
    for (int i = 0; i < 4; ++i) {
        half8 hw = wgt[(size_t)g4 * 4 + i];
        float acc = bv[i];
        acc += (float)hw[0] * um[i]     + (float)hw[1] * um[i + 1] + (float)hw[2] * um[i + 2];
        acc += (float)hw[3] * cc[i]     + (float)hw[4] * cc[i + 2];
        acc += (float)hw[5] * dn[i]     + (float)hw[6] * dn[i + 1] + (float)hw[7] * dn[i + 2];
        out[i] = acc;
    }
    *(float4*)(dst + (size_t)g4 * 4) = make_float4(out[0], out[1], out[2], out[3]);
}

// ---------------------------------------------------------------------------
extern "C" void kernel_launch(void* const* d_in, const int* in_sizes, int n_in,
                              void* d_out, int out_size, void* d_ws, size_t ws_size,
                              hipStream_t stream) {
    const float* guidance = (const float*)d_in[0];
    const float* raw      = (const float*)d_in[1];
    float* out = (float*)d_out;

    const int B = 8, H = 480, W = 640;
    const int PROP_TIME = 24;
    const size_t npix = (size_t)B * H * W;

    // Workspace layout: fp16 weights (npix * 16B) | bias (npix f32) | tmp (npix f32)
    half8* wgt  = (half8*)d_ws;
    float* bias = (float*)((char*)d_ws + npix * sizeof(half8));
    float* tmpb = bias + npix;

    {
        int total = (int)npix;
        int blocks = (total + 255) / 256;
        precompute_kernel<<<blocks, 256, 0, stream>>>(guidance, raw, wgt, bias,
                                                      out, B, H, W);
    }

    int total4 = (int)(npix / 4);
    int blocks = (total4 + 255) / 256;
    float* a = out;   // result lives here after init
    float* bb = tmpb;
    for (int t = 0; t < PROP_TIME; ++t) {
        prop_kernel<<<blocks, 256, 0, stream>>>(a, wgt, bias, bb, B, H, W);
        float* sw = a; a = bb; bb = sw;
    }
    // PROP_TIME is even -> final result is back in d_out.
}

// Round 3
// 303.004 us; speedup vs baseline: 1.7002x; 1.1319x over previous
//
#include <hip/hip_runtime.h>
#include <hip/hip_fp16.h>

// Affinity propagation: 24 Jacobi iterations of an 8-neighbor weighted stencil.
// OFFSETS (dy,dx): (-1,-1),(-1,0),(-1,1),(0,-1),(0,1),(1,-1),(1,0),(1,1)
// R3: fuse 3 iterations per launch with overlapped (trapezoidal) LDS tiling.
// Weights fp16 AoS (16 B/px); bias fp32; src/dst fp32 planes.

#define EPSV 1e-6f

#define TILE_H 32
#define TILE_W 64
#define FUSE   3
#define SRC_H  (TILE_H + 2 * FUSE)   // 38
#define SRC_W  (TILE_W + 2 * FUSE)   // 70
#define LDS_W  (SRC_W + 2)           // 72 (pad; x-consecutive access is conflict-free anyway)

typedef __attribute__((ext_vector_type(8))) _Float16 half8;

// ---------------------------------------------------------------------------
// Kernel 1: normalize guidance -> per-pixel 8 fp16 weights (AoS), fp32 bias,
// init out = raw.
// ---------------------------------------------------------------------------
__global__ __launch_bounds__(256) void precompute_kernel(
    const float* __restrict__ guidance, const float* __restrict__ raw,
    half8* __restrict__ wgt, float* __restrict__ bias, float* __restrict__ out,
    int B, int H, int W)
{
    int idx = blockIdx.x * blockDim.x + threadIdx.x;
    int total = B * H * W;
    if (idx >= total) return;
    int x = idx % W;
    int y = (idx / W) % H;
    int b = idx / (W * H);

    const int dy[8] = {-1,-1,-1, 0, 0, 1, 1, 1};
    const int dx[8] = {-1, 0, 1,-1, 1,-1, 0, 1};

    float g[8];
    float s = 0.f;
#pragma unroll
    for (int c = 0; c < 8; ++c) {
        int yy = y + dy[c], xx = x + dx[c];
        float v = 0.f;
        if (yy >= 0 && yy < H && xx >= 0 && xx < W)
            v = guidance[(((size_t)b * 8 + c) * H + yy) * W + xx];
        g[c] = v;
        s += fabsf(v);
    }
    float inv = 1.f / fmaxf(s, EPSV);
    float wsum = 0.f;
#pragma unroll
    for (int c = 0; c < 8; ++c) { g[c] *= inv; wsum += g[c]; }

    half8 hw;
#pragma unroll
    for (int c = 0; c < 8; ++c) hw[c] = (_Float16)g[c];
    wgt[idx] = hw;

    float r = raw[idx];
    bias[idx] = (1.f - wsum) * r;
    out[idx] = r;
}

// ---------------------------------------------------------------------------
// Kernel 2: FUSE iterations per launch, overlapped tiling.
// Block computes a TILE_H x TILE_W output tile. All LDS buffers share origin
// (y0-FUSE, x0-FUSE). Iteration k (1..FUSE) computes region of size
// (TILE_H+2*(FUSE-k)) x (TILE_W+2*(FUSE-k)) starting at buffer coord (k,k).
// Out-of-image positions get value 0 (matches zero-pad semantics).
// ---------------------------------------------------------------------------
__global__ __launch_bounds__(256) void prop_fused_kernel(
    const float* __restrict__ src, const half8* __restrict__ wgt,
    const float* __restrict__ bias, float* __restrict__ dst,
    int B, int H, int W)
{
    __shared__ float bufA[SRC_H][LDS_W];
    __shared__ float bufB[SRC_H][LDS_W];

    int tilesX = W / TILE_W;              // 10
    int tilesY = H / TILE_H;              // 15
    int bid = blockIdx.x;
    int tx = bid % tilesX;
    int tmp = bid / tilesX;
    int ty = tmp % tilesY;
    int b  = tmp / tilesY;
    int x0 = tx * TILE_W;
    int y0 = ty * TILE_H;
    int tid = threadIdx.x;

    const float* splane = src + (size_t)b * H * W;
    const size_t plane_off = (size_t)b * H * W;

    // Stage src region into bufA (zero outside image).
    for (int i = tid; i < SRC_H * SRC_W; i += 256) {
        int ry = i / SRC_W, rx = i % SRC_W;
        int gy = y0 - FUSE + ry, gx = x0 - FUSE + rx;
        float v = 0.f;
        if (gy >= 0 && gy < H && gx >= 0 && gx < W)
            v = splane[(size_t)gy * W + gx];
        bufA[ry][rx] = v;
    }
    __syncthreads();

    float (*cur)[LDS_W] = bufA;
    float (*nxt)[LDS_W] = bufB;

#pragma unroll
    for (int k = 1; k <= FUSE; ++k) {
        const int RH = TILE_H + 2 * (FUSE - k);
        const int RW = TILE_W + 2 * (FUSE - k);
        for (int i = tid; i < RH * RW; i += 256) {
            int ry = i / RW, rx = i % RW;
            int by = k + ry, bx = k + rx;          // buffer coords
            int gy = y0 - FUSE + by, gx = x0 - FUSE + bx;
            float m = 0.f;
            if (gy >= 0 && gy < H && gx >= 0 && gx < W) {
                size_t gidx = plane_off + (size_t)gy * W + gx;
                half8 hw = wgt[gidx];
                float acc = bias[gidx];
                acc += (float)hw[0] * cur[by - 1][bx - 1];
                acc += (float)hw[1] * cur[by - 1][bx    ];
                acc += (float)hw[2] * cur[by - 1][bx + 1];
                acc += (float)hw[3] * cur[by    ][bx - 1];
                acc += (float)hw[4] * cur[by    ][bx + 1];
                acc += (float)hw[5] * cur[by + 1][bx - 1];
                acc += (float)hw[6] * cur[by + 1][bx    ];
                acc += (float)hw[7] * cur[by + 1][bx + 1];
                m = acc;
            }
            if (k == FUSE) {
                if (m != 0.f || true) dst[plane_off + (size_t)gy * W + gx] = m;
            } else {
                nxt[by][bx] = m;
            }
        }
        if (k != FUSE) {
            __syncthreads();
            float (*sw)[LDS_W] = cur; cur = nxt; nxt = sw;
        }
    }
}

// ---------------------------------------------------------------------------
extern "C" void kernel_launch(void* const* d_in, const int* in_sizes, int n_in,
                              void* d_out, int out_size, void* d_ws, size_t ws_size,
                              hipStream_t stream) {
    const float* guidance = (const float*)d_in[0];
    const float* raw      = (const float*)d_in[1];
    float* out = (float*)d_out;

    const int B = 8, H = 480, W = 640;
    const int PROP_TIME = 24;            // = FUSE * 8 fused launches
    const size_t npix = (size_t)B * H * W;

    // Workspace: fp16 weights (npix*16B) | bias (npix f32) | tmp (npix f32)
    half8* wgt  = (half8*)d_ws;
    float* bias = (float*)((char*)d_ws + npix * sizeof(half8));
    float* tmpb = bias + npix;

    {
        int total = (int)npix;
        int blocks = (total + 255) / 256;
        precompute_kernel<<<blocks, 256, 0, stream>>>(guidance, raw, wgt, bias,
                                                      out, B, H, W);
    }

    const int nlaunch = PROP_TIME / FUSE;          // 8 (even -> ends in d_out)
    int blocks = B * (H / TILE_H) * (W / TILE_W);  // 8*15*10 = 1200
    float* a = out;
    float* bb = tmpb;
    for (int t = 0; t < nlaunch; ++t) {
        prop_fused_kernel<<<blocks, 256, 0, stream>>>(a, wgt, bias, bb, B, H, W);
        float* sw = a; a = bb; bb = sw;
    }
}

// Round 4
// 201.547 us; speedup vs baseline: 2.5560x; 1.5034x over previous
//
#include <hip/hip_runtime.h>
#include <hip/hip_fp16.h>

// Affinity propagation: 24 Jacobi iterations of an 8-neighbor weighted stencil.
// OFFSETS (dy,dx): (-1,-1),(-1,0),(-1,1),(0,-1),(0,1),(1,-1),(1,0),(1,1)
// R4: FUSE=4 iterations per launch; weights+bias held in REGISTERS (read once
// per launch), src plane ping-pongs in LDS with a zero ring (no edge guards).

#define EPSV 1e-6f

#define TILE_H 32
#define TILE_W 64
#define FUSE   4
#define IN_H   (TILE_H + 2 * FUSE)      // 40
#define IN_W   (TILE_W + 2 * FUSE)      // 72
#define BUF_H  (IN_H + 2)               // 42 (zero ring)
#define BUF_W  (IN_W + 2)               // 74
#define NPX    (IN_H * IN_W)            // 2880
#define NSLOT  ((NPX + 255) / 256)      // 12

typedef __attribute__((ext_vector_type(8))) _Float16 half8;

// ---------------------------------------------------------------------------
// Kernel 1: normalize guidance -> per-pixel 8 fp16 weights (AoS), fp32 bias,
// init out = raw.
// ---------------------------------------------------------------------------
__global__ __launch_bounds__(256) void precompute_kernel(
    const float* __restrict__ guidance, const float* __restrict__ raw,
    half8* __restrict__ wgt, float* __restrict__ bias, float* __restrict__ out,
    int B, int H, int W)
{
    int idx = blockIdx.x * blockDim.x + threadIdx.x;
    int total = B * H * W;
    if (idx >= total) return;
    int x = idx % W;
    int y = (idx / W) % H;
    int b = idx / (W * H);

    const int dy[8] = {-1,-1,-1, 0, 0, 1, 1, 1};
    const int dx[8] = {-1, 0, 1,-1, 1,-1, 0, 1};

    float g[8];
    float s = 0.f;
#pragma unroll
    for (int c = 0; c < 8; ++c) {
        int yy = y + dy[c], xx = x + dx[c];
        float v = 0.f;
        if (yy >= 0 && yy < H && xx >= 0 && xx < W)
            v = guidance[(((size_t)b * 8 + c) * H + yy) * W + xx];
        g[c] = v;
        s += fabsf(v);
    }
    float inv = 1.f / fmaxf(s, EPSV);
    float wsum = 0.f;
#pragma unroll
    for (int c = 0; c < 8; ++c) { g[c] *= inv; wsum += g[c]; }

    half8 hw;
#pragma unroll
    for (int c = 0; c < 8; ++c) hw[c] = (_Float16)g[c];
    wgt[idx] = hw;

    float r = raw[idx];
    bias[idx] = (1.f - wsum) * r;
    out[idx] = r;
}

// ---------------------------------------------------------------------------
// Kernel 2: FUSE fused Jacobi iterations. Block owns a TILE_H x TILE_W output
// tile; LDS holds the padded (IN_H x IN_W) plane inside a zero ring. Each
// thread owns NSLOT fixed pixels; their weights/bias live in registers for
// all FUSE iterations. Full interior is recomputed each iteration
// (zero-outside-buffer); after k iterations pixels >= k from the buffer edge
// are exact, so the center tile is exact at k == FUSE. Out-of-image pixels
// have w=0,b=0 -> remain 0, matching zero-pad semantics.
// ---------------------------------------------------------------------------
__global__ __launch_bounds__(256) void prop_fused_kernel(
    const float* __restrict__ src, const half8* __restrict__ wgt,
    const float* __restrict__ bias, float* __restrict__ dst,
    int B, int H, int W)
{
    __shared__ float bufA[BUF_H][BUF_W];
    __shared__ float bufB[BUF_H][BUF_W];

    int tilesX = W / TILE_W;              // 10
    int tilesY = H / TILE_H;              // 15
    int bid = blockIdx.x;
    int tx = bid % tilesX;
    int tmp = bid / tilesX;
    int ty = tmp % tilesY;
    int b  = tmp / tilesY;
    int x0 = tx * TILE_W - FUSE;          // global coord of interior origin
    int y0 = ty * TILE_H - FUSE;
    int tid = threadIdx.x;
    const size_t plane = (size_t)b * H * W;

    // Zero both buffers (the 1-px ring must be 0; interior overwritten below).
    for (int i = tid; i < BUF_H * BUF_W; i += 256) {
        (&bufA[0][0])[i] = 0.f;
        (&bufB[0][0])[i] = 0.f;
    }
    __syncthreads();

    // Load per-slot weights/bias into registers; stage src into bufA interior.
    half8 w[NSLOT];
    float bv[NSLOT];
#pragma unroll
    for (int j = 0; j < NSLOT; ++j) {
        int p = j * 256 + tid;
        int ry = p / IN_W, rx = p % IN_W;
        int gy = y0 + ry, gx = x0 + rx;
        bool ok = (p < NPX) && gy >= 0 && gy < H && gx >= 0 && gx < W;
        half8 hw;
#pragma unroll
        for (int c = 0; c < 8; ++c) hw[c] = (_Float16)0.f;
        float bb = 0.f, sv = 0.f;
        if (ok) {
            size_t gidx = plane + (size_t)gy * W + gx;
            hw = wgt[gidx];
            bb = bias[gidx];
            sv = src[gidx];
        }
        w[j] = hw;
        bv[j] = bb;
        if (p < NPX) bufA[ry + 1][rx + 1] = sv;
    }
    __syncthreads();

    float (*cur)[BUF_W] = bufA;
    float (*nxt)[BUF_W] = bufB;

#pragma unroll
    for (int k = 1; k <= FUSE; ++k) {
#pragma unroll
        for (int j = 0; j < NSLOT; ++j) {
            int p = j * 256 + tid;
            if (p < NPX) {
                int ry = p / IN_W + 1, rx = p % IN_W + 1;   // ring coords
                float acc = bv[j];
                acc += (float)w[j][0] * cur[ry - 1][rx - 1];
                acc += (float)w[j][1] * cur[ry - 1][rx    ];
                acc += (float)w[j][2] * cur[ry - 1][rx + 1];
                acc += (float)w[j][3] * cur[ry    ][rx - 1];
                acc += (float)w[j][4] * cur[ry    ][rx + 1];
                acc += (float)w[j][5] * cur[ry + 1][rx - 1];
                acc += (float)w[j][6] * cur[ry + 1][rx    ];
                acc += (float)w[j][7] * cur[ry + 1][rx + 1];
                if (k == FUSE) {
                    int iry = ry - 1, irx = rx - 1;         // interior coords
                    if (iry >= FUSE && iry < FUSE + TILE_H &&
                        irx >= FUSE && irx < FUSE + TILE_W) {
                        int gy = y0 + iry, gx = x0 + irx;
                        dst[plane + (size_t)gy * W + gx] = acc;
                    }
                } else {
                    nxt[ry][rx] = acc;
                }
            }
        }
        if (k != FUSE) {
            __syncthreads();
            float (*sw)[BUF_W] = cur; cur = nxt; nxt = sw;
        }
    }
}

// ---------------------------------------------------------------------------
extern "C" void kernel_launch(void* const* d_in, const int* in_sizes, int n_in,
                              void* d_out, int out_size, void* d_ws, size_t ws_size,
                              hipStream_t stream) {
    const float* guidance = (const float*)d_in[0];
    const float* raw      = (const float*)d_in[1];
    float* out = (float*)d_out;

    const int B = 8, H = 480, W = 640;
    const int PROP_TIME = 24;            // = FUSE * 6 fused launches
    const size_t npix = (size_t)B * H * W;

    // Workspace: fp16 weights (npix*16B) | bias (npix f32) | tmp (npix f32)
    half8* wgt  = (half8*)d_ws;
    float* bias = (float*)((char*)d_ws + npix * sizeof(half8));
    float* tmpb = bias + npix;

    {
        int total = (int)npix;
        int blocks = (total + 255) / 256;
        precompute_kernel<<<blocks, 256, 0, stream>>>(guidance, raw, wgt, bias,
                                                      out, B, H, W);
    }

    const int nlaunch = PROP_TIME / FUSE;          // 6 (even -> ends in d_out)
    int blocks = B * (H / TILE_H) * (W / TILE_W);  // 8*15*10 = 1200
    float* a = out;
    float* bb = tmpb;
    for (int t = 0; t < nlaunch; ++t) {
        prop_fused_kernel<<<blocks, 256, 0, stream>>>(a, wgt, bias, bb, B, H, W);
        float* sw = a; a = bb; bb = sw;
    }
}

// Round 5
// 177.380 us; speedup vs baseline: 2.9042x; 1.1362x over previous
//
#include <hip/hip_runtime.h>
#include <hip/hip_fp16.h>

// Affinity propagation: 24 Jacobi iterations of an 8-neighbor weighted stencil.
// OFFSETS (dy,dx): (-1,-1),(-1,0),(-1,1),(0,-1),(0,1),(1,-1),(1,0),(1,1)
// R5: FUSE=4 per launch; thread owns 3 horizontal quads (4 px). Weights+bias
// in registers for the whole launch; LDS reads vectorized (b128+b64 per row);
// ping-pong state planes in fp16 (f32 inside LDS). Final launch writes f32.

#define EPSV 1e-6f

#define TILE_H 32
#define TILE_W 64
#define FUSE   4
#define IN_H   (TILE_H + 2 * FUSE)      // 40
#define IN_W   (TILE_W + 2 * FUSE)      // 72
#define BUF_H  (IN_H + 2)               // 42 (zero ring)
#define BUF_W  76                       // 74 padded to mult-of-4 -> 16B rows
#define QPR    (IN_W / 4)               // 18 quads per row
#define NQUAD  (IN_H * QPR)             // 720
#define NSLOT  3                        // ceil(720/256)

typedef __attribute__((ext_vector_type(8))) _Float16 half8;
typedef __attribute__((ext_vector_type(4))) _Float16 half4;

// ---------------------------------------------------------------------------
// Kernel 1: normalize guidance -> fp16 weights (AoS), fp16 bias, fp16 state.
// ---------------------------------------------------------------------------
__global__ __launch_bounds__(256) void precompute_kernel(
    const float* __restrict__ guidance, const float* __restrict__ raw,
    half8* __restrict__ wgt, _Float16* __restrict__ bias,
    _Float16* __restrict__ state, int B, int H, int W)
{
    int idx = blockIdx.x * blockDim.x + threadIdx.x;
    int total = B * H * W;
    if (idx >= total) return;
    int x = idx % W;
    int y = (idx / W) % H;
    int b = idx / (W * H);

    const int dy[8] = {-1,-1,-1, 0, 0, 1, 1, 1};
    const int dx[8] = {-1, 0, 1,-1, 1,-1, 0, 1};

    float g[8];
    float s = 0.f;
#pragma unroll
    for (int c = 0; c < 8; ++c) {
        int yy = y + dy[c], xx = x + dx[c];
        float v = 0.f;
        if (yy >= 0 && yy < H && xx >= 0 && xx < W)
            v = guidance[(((size_t)b * 8 + c) * H + yy) * W + xx];
        g[c] = v;
        s += fabsf(v);
    }
    float inv = 1.f / fmaxf(s, EPSV);
    float wsum = 0.f;
#pragma unroll
    for (int c = 0; c < 8; ++c) { g[c] *= inv; wsum += g[c]; }

    half8 hw;
#pragma unroll
    for (int c = 0; c < 8; ++c) hw[c] = (_Float16)g[c];
    wgt[idx] = hw;

    float r = raw[idx];
    bias[idx]  = (_Float16)((1.f - wsum) * r);
    state[idx] = (_Float16)r;
}

// ---------------------------------------------------------------------------
// Kernel 2: FUSE fused Jacobi iterations. Block owns TILE_H x TILE_W output;
// LDS holds padded IN_H x IN_W plane inside a zero ring. Thread owns NSLOT
// quads (4 consecutive px); their weights/bias stay in registers all FUSE
// iterations. Full interior recomputed per iteration (zero-outside-buffer):
// after k iters, pixels >= k from the buffer edge are exact -> center tile
// exact at k == FUSE. Out-of-image pixels have w=0,b=0 -> stay 0 (zero-pad).
// ---------------------------------------------------------------------------
template<bool LAST>
__global__ __launch_bounds__(256) void prop_fused_kernel(
    const _Float16* __restrict__ src, const half8* __restrict__ wgt,
    const _Float16* __restrict__ bias, _Float16* __restrict__ dst,
    float* __restrict__ dst32)
{
    const int B = 8, H = 480, W = 640;
    __shared__ __align__(16) float bufA[BUF_H][BUF_W];
    __shared__ __align__(16) float bufB[BUF_H][BUF_W];

    int tilesX = W / TILE_W;              // 10
    int tilesY = H / TILE_H;              // 15
    int bid = blockIdx.x;
    int tx = bid % tilesX;
    int tmp = bid / tilesX;
    int ty = tmp % tilesY;
    int b  = tmp / tilesY;
    int x0 = tx * TILE_W - FUSE;
    int y0 = ty * TILE_H - FUSE;
    int tid = threadIdx.x;
    const size_t plane = (size_t)b * H * W;

    for (int i = tid; i < BUF_H * BUF_W; i += 256) {
        (&bufA[0][0])[i] = 0.f;
        (&bufB[0][0])[i] = 0.f;
    }
    __syncthreads();

    half8 w[NSLOT][4];
    float bv[NSLOT][4];
    int   loff[NSLOT];       // LDS float-offset of up-row read start
    size_t goff[NSLOT];      // global pixel index of quad start
    bool  act[NSLOT], core[NSLOT];

#pragma unroll
    for (int j = 0; j < NSLOT; ++j) {
        int q = j * 256 + tid;
        act[j] = (q < NQUAD);
        int qq = act[j] ? q : 0;
        int ry = qq / QPR, rx0 = (qq % QPR) * 4;
        int gy = y0 + ry, gx = x0 + rx0;
        bool ok = act[j] && gy >= 0 && gy < H && gx >= 0 && gx < W;
        // up-row read start: ring row (ry+1)-1 = ry, ring col (rx0+1)-1 = rx0
        loff[j] = ry * BUF_W + rx0;
        size_t gb = plane + (size_t)gy * W + gx;
        goff[j] = gb;
        core[j] = act[j] && ry >= FUSE && ry < FUSE + TILE_H &&
                  rx0 >= FUSE && rx0 < FUSE + TILE_W;

        half8 z;
#pragma unroll
        for (int c = 0; c < 8; ++c) z[c] = (_Float16)0.f;
        w[j][0] = z; w[j][1] = z; w[j][2] = z; w[j][3] = z;
        bv[j][0] = bv[j][1] = bv[j][2] = bv[j][3] = 0.f;
        float s0 = 0.f, s1 = 0.f, s2 = 0.f, s3 = 0.f;
        if (ok) {
            const half8* wp = wgt + gb;               // 64B contiguous
            w[j][0] = wp[0]; w[j][1] = wp[1]; w[j][2] = wp[2]; w[j][3] = wp[3];
            half4 bq = *(const half4*)(bias + gb);    // 8B aligned (gb%4==0)
            bv[j][0] = (float)bq[0]; bv[j][1] = (float)bq[1];
            bv[j][2] = (float)bq[2]; bv[j][3] = (float)bq[3];
            half4 sq = *(const half4*)(src + gb);
            s0 = (float)sq[0]; s1 = (float)sq[1];
            s2 = (float)sq[2]; s3 = (float)sq[3];
        }
        if (act[j]) {
            float* d = &bufA[0][0] + loff[j] + BUF_W + 1;   // interior px
            d[0] = s0; d[1] = s1; d[2] = s2; d[3] = s3;
        }
    }
    __syncthreads();

#pragma unroll
    for (int k = 0; k < FUSE; ++k) {
        const float* cur = (k & 1) ? &bufB[0][0] : &bufA[0][0];
        float* nxt       = (k & 1) ? &bufA[0][0] : &bufB[0][0];
#pragma unroll
        for (int j = 0; j < NSLOT; ++j) {
            const float* up = cur + loff[j];
            const float* ct = up + BUF_W;
            const float* dn = ct + BUF_W;
            float4 u4 = *(const float4*)up;  float2 u2 = *(const float2*)(up + 4);
            float4 c4 = *(const float4*)ct;  float2 c2 = *(const float2*)(ct + 4);
            float4 d4 = *(const float4*)dn;  float2 d2 = *(const float2*)(dn + 4);
            float u[6]  = {u4.x, u4.y, u4.z, u4.w, u2.x, u2.y};
            float cc[6] = {c4.x, c4.y, c4.z, c4.w, c2.x, c2.y};
            float dd[6] = {d4.x, d4.y, d4.z, d4.w, d2.x, d2.y};
            float acc[4];
#pragma unroll
            for (int i = 0; i < 4; ++i) {
                half8 hw = w[j][i];
                float a = bv[j][i];
                a += (float)hw[0] * u[i]  + (float)hw[1] * u[i + 1] + (float)hw[2] * u[i + 2];
                a += (float)hw[3] * cc[i] + (float)hw[4] * cc[i + 2];
                a += (float)hw[5] * dd[i] + (float)hw[6] * dd[i + 1] + (float)hw[7] * dd[i + 2];
                acc[i] = a;
            }
            if (k < FUSE - 1) {
                if (act[j]) {
                    float* o = nxt + loff[j] + BUF_W + 1;
                    o[0] = acc[0]; o[1] = acc[1]; o[2] = acc[2]; o[3] = acc[3];
                }
            } else {
                if (core[j]) {
                    if (LAST) {
                        *(float4*)(dst32 + goff[j]) =
                            make_float4(acc[0], acc[1], acc[2], acc[3]);
                    } else {
                        half4 hv;
                        hv[0] = (_Float16)acc[0]; hv[1] = (_Float16)acc[1];
                        hv[2] = (_Float16)acc[2]; hv[3] = (_Float16)acc[3];
                        *(half4*)(dst + goff[j]) = hv;
                    }
                }
            }
        }
        if (k < FUSE - 1) __syncthreads();
    }
}

// ---------------------------------------------------------------------------
extern "C" void kernel_launch(void* const* d_in, const int* in_sizes, int n_in,
                              void* d_out, int out_size, void* d_ws, size_t ws_size,
                              hipStream_t stream) {
    const float* guidance = (const float*)d_in[0];
    const float* raw      = (const float*)d_in[1];
    float* out = (float*)d_out;

    const int B = 8, H = 480, W = 640;
    const size_t npix = (size_t)B * H * W;

    // Workspace: wgt half8 (npix*16B) | bias fp16 | p0 fp16 | p1 fp16
    half8*    wgt  = (half8*)d_ws;
    _Float16* bias = (_Float16*)((char*)d_ws + npix * sizeof(half8));
    _Float16* p0   = bias + npix;
    _Float16* p1   = p0 + npix;

    {
        int blocks = (int)((npix + 255) / 256);
        precompute_kernel<<<blocks, 256, 0, stream>>>(guidance, raw, wgt, bias,
                                                      p0, B, H, W);
    }

    int blocks = B * (H / TILE_H) * (W / TILE_W);   // 1200
    // 6 launches x FUSE=4 = 24 iterations. State: p0 -> p1 -> p0 ... final
    // launch reads p1 (after 5 hops state is in p1) ... sequence below.
    _Float16* a = p0;
    _Float16* bb = p1;
    for (int t = 0; t < 5; ++t) {
        prop_fused_kernel<false><<<blocks, 256, 0, stream>>>(a, wgt, bias, bb,
                                                             nullptr);
        _Float16* sw = a; a = bb; bb = sw;
    }
    prop_fused_kernel<true><<<blocks, 256, 0, stream>>>(a, wgt, bias, nullptr,
                                                        out);
}